// Round 7
// baseline (1466.537 us; speedup 1.0000x reference)
//
#include <hip/hip_runtime.h>
#include <math.h>

#define BATCH 8
#define N_PTS 4096
#define KNN 20
#define EPS_BN 1e-5f
#define SLOPE 0.2f
#define M_ROWS (BATCH * N_PTS)

typedef __attribute__((ext_vector_type(8))) short short8;      // bf16 x8 (4 VGPR)
typedef __attribute__((ext_vector_type(4))) float float4v;     // fp32 x4 acc
typedef __attribute__((ext_vector_type(16))) float float16v;   // fp32 x16 acc

__device__ __forceinline__ unsigned short f2bf(float f) {
    unsigned u = __float_as_uint(f);
    unsigned r = (u + 0x7FFFu + ((u >> 16) & 1u)) >> 16;
    return (unsigned short)r;
}
__device__ __forceinline__ float bf2f(unsigned short h) {
    return __uint_as_float((unsigned)h << 16);
}

// ---------------------------------------------------------------------------
// x (B,3,N) fp32 -> x1h/x1l (M,32) bf16 split (zero-padded), + sq norms
__global__ void convert_x1(const float* __restrict__ x,
                           unsigned short* __restrict__ xh, unsigned short* __restrict__ xl,
                           float* __restrict__ sq) {
    int i = blockIdx.x * blockDim.x + threadIdx.x;
    if (i >= M_ROWS) return;
    int b = i / N_PTS, n = i % N_PTS;
    float v[3], s = 0.f;
    #pragma unroll
    for (int d = 0; d < 3; ++d) {
        v[d] = x[((size_t)b * 3 + d) * N_PTS + n];
        s += v[d] * v[d];
    }
    sq[i] = s;
    #pragma unroll
    for (int d = 0; d < 32; ++d) {
        float f = (d < 3) ? v[d] : 0.f;
        unsigned short h = f2bf(f);
        xh[(size_t)i * 32 + d] = h;
        xl[(size_t)i * 32 + d] = f2bf(f - bf2f(h));
    }
}

// sq norms from bf16 hi/lo feature rows (stride 512)
__global__ void sqnorm_hl(const unsigned short* __restrict__ hh,
                          const unsigned short* __restrict__ hl,
                          int D, float* __restrict__ sq) {
    int w = threadIdx.x >> 6, lane = threadIdx.x & 63;
    int row = blockIdx.x * 4 + w;
    if (row >= M_ROWS) return;
    const unsigned short* ph = hh + (size_t)row * 512;
    const unsigned short* pl = hl + (size_t)row * 512;
    float s = 0.f;
    for (int d = lane; d < D; d += 64) {
        float v = bf2f(ph[d]) + bf2f(pl[d]);
        s += v * v;
    }
    #pragma unroll
    for (int off = 32; off > 0; off >>= 1) s += __shfl_down(s, off, 64);
    if (lane == 0) sq[row] = s;
}

// ---------------------------------------------------------------------------
// weight repacks -> bf16 hi/lo, B-operand layout [C][KP] (k contiguous)
__global__ void repack_edge_split(const float* __restrict__ W, int Co, int D, int KP,
                                  unsigned short* __restrict__ Wh, unsigned short* __restrict__ Wl) {
    int i = blockIdx.x * blockDim.x + threadIdx.x;
    int tot = 2 * Co * KP;
    if (i >= tot) return;
    int r = i / KP, d = i % KP;
    float v = 0.f;
    if (d < D) v = (r < Co) ? W[(size_t)r * 2 * D + d] : W[(size_t)(r - Co) * 2 * D + D + d];
    unsigned short h = f2bf(v);
    Wh[i] = h; Wl[i] = f2bf(v - bf2f(h));
}

__global__ void repack_w5_split(const float* __restrict__ W,
                                unsigned short* __restrict__ Wh, unsigned short* __restrict__ Wl) {
    int i = blockIdx.x * blockDim.x + threadIdx.x;
    if (i >= 512 * 512) return;
    float v = W[i];
    unsigned short h = f2bf(v);
    Wh[i] = h; Wl[i] = f2bf(v - bf2f(h));
}

// ---------------------------------------------------------------------------
// MFMA KNN v7: barrier-free main loop. A = candidates (regs<-global direct),
// B = queries (regs, loaded once). C/D: lane owns one query col, 16 candidate
// scores in regs -> per-lane streaming top-20, lane-private LDS scratch for
// mask-batched insert. grid: (N/64, B), block 256.
// Wave w: queries (w&1)*32 + l31; candidate group (w>>1)*32, step 64/tile.
template<int DPAD>
__launch_bounds__(256, 2)
__global__ void knn_mfma(const unsigned short* __restrict__ Xh,
                         const unsigned short* __restrict__ Xl,
                         int strideX,
                         const float* __restrict__ sq, int* __restrict__ idxout) {
    constexpr int KS = DPAD / 16;     // mfma K=16 steps
    // LDS pool: main phase = sqs[4096] + scr[256*17]; merge phase = kb/ib[5120]
    constexpr size_t MAIN  = (size_t)4096 * 4 + (size_t)256 * 17 * 4;
    constexpr size_t MERGE = (size_t)64 * 4 * KNN * 8;
    constexpr size_t POOL  = MAIN > MERGE ? MAIN : MERGE;
    __shared__ __align__(16) char smem[POOL];
    float* sqs = (float*)smem;                 // [4096]
    float* scr = sqs + 4096;                   // [256*17] lane-private scores
    float*    kb = (float*)smem;               // merge vals [64][4][KNN]
    unsigned* ib = (unsigned*)(kb + 64 * 4 * KNN);

    const int b = blockIdx.y;
    const int row0 = blockIdx.x * 64;
    const int tid = threadIdx.x;
    const int w = tid >> 6, lane = tid & 63;
    const int l31 = lane & 31, lh = lane >> 5;
    const int qg = w & 1, cg = w >> 1;

    const unsigned short* Xhb = Xh + (size_t)b * N_PTS * strideX;
    const unsigned short* Xlb = Xl + (size_t)b * N_PTS * strideX;
    const float* sqb = sq + (size_t)b * N_PTS;

    // stage sq table (16 KB), once
    {
        const float4v* s4 = (const float4v*)sqb;
        float4v* d4 = (float4v*)sqs;
        #pragma unroll
        for (int it = 0; it < 4; ++it) d4[tid + it * 256] = s4[tid + it * 256];
    }
    __syncthreads();

    // queries -> registers (once): row = row0 + qg*32 + l31, k = ks*16 + lh*8
    short8 qh[KS], ql[KS];
    {
        size_t qo = (size_t)(row0 + qg * 32 + l31) * strideX + lh * 8;
        #pragma unroll
        for (int ks = 0; ks < KS; ++ks) {
            qh[ks] = *(const short8*)(Xhb + qo + ks * 16);
            ql[ks] = *(const short8*)(Xlb + qo + ks * 16);
        }
    }

    // per-lane top-20 (exact fp32 val + idx), ascending by (val, idx)
    float fv[KNN]; int fi[KNN];
    #pragma unroll
    for (int p = 0; p < KNN; ++p) { fv[p] = INFINITY; fi[p] = 0x7FFFFFFF; }

    const int scrb = tid * 17;

    #pragma unroll 1
    for (int c0 = 0; c0 < N_PTS; c0 += 64) {
        const int cbase = c0 + cg * 32;
        // candidate A-frags direct from global (L1/L2 resident)
        short8 ch[KS], cl[KS];
        size_t ro = (size_t)(cbase + l31) * strideX + lh * 8;
        #pragma unroll
        for (int ks = 0; ks < KS; ++ks) {
            ch[ks] = *(const short8*)(Xhb + ro + ks * 16);
            cl[ks] = *(const short8*)(Xlb + ro + ks * 16);
        }

        float16v acc = {};
        #pragma unroll
        for (int ks = 0; ks < KS; ++ks) {
            acc = __builtin_amdgcn_mfma_f32_32x32x16_bf16(ch[ks], qh[ks], acc, 0, 0, 0);
            acc = __builtin_amdgcn_mfma_f32_32x32x16_bf16(cl[ks], qh[ks], acc, 0, 0, 0);
            acc = __builtin_amdgcn_mfma_f32_32x32x16_bf16(ch[ks], ql[ks], acc, 0, 0, 0);
        }

        // scores: candidate row for reg = (reg&3) + 8*(reg>>2) + 4*lh
        unsigned mask = 0;
        #pragma unroll
        for (int reg = 0; reg < 16; ++reg) {
            int crow = (reg & 3) + 8 * (reg >> 2) + 4 * lh;
            float v = fmaf(-2.f, acc[reg], sqs[cbase + crow]);   // sq[q] dropped: const/query
            scr[scrb + reg] = v;
            if (v < fv[KNN - 1]) mask |= (1u << reg);
        }
        while (mask) {
            int jj = __ffs(mask) - 1;
            mask &= mask - 1;
            float v = scr[scrb + jj];
            if (v < fv[KNN - 1]) {    // strict '<': ascending-idx stream, stable ties
                fv[KNN - 1] = v;
                fi[KNN - 1] = cbase + (jj & 3) + 8 * (jj >> 2) + 4 * lh;
                #pragma unroll
                for (int p = KNN - 1; p > 0; --p) {
                    float va = fv[p - 1], vb = fv[p];
                    int   ia = fi[p - 1], ic = fi[p];
                    bool sw = vb < va;
                    fv[p - 1] = sw ? vb : va; fv[p] = sw ? va : vb;
                    fi[p - 1] = sw ? ic : ia; fi[p] = sw ? ia : ic;
                }
            }
        }
    }
    __syncthreads();   // main-loop LDS (sqs/scr) dead; reuse pool for merge

    // dump per-lane lists: query qloc = qg*32+l31, list = cg*2+lh
    {
        int qloc = qg * 32 + l31;
        int list = cg * 2 + lh;
        int base = (qloc * 4 + list) * KNN;
        #pragma unroll
        for (int p = 0; p < KNN; ++p) { kb[base + p] = fv[p]; ib[base + p] = (unsigned)fi[p]; }
    }
    __syncthreads();

    // lex-stable merge of 4 sorted lists per query, threads 0..63
    if (tid < 64) {
        int base = tid * 4 * KNN;
        #pragma unroll
        for (int p = 0; p < KNN; ++p) { fv[p] = kb[base + p]; fi[p] = (int)ib[base + p]; }
        #pragma unroll 1
        for (int qq = KNN; qq < 4 * KNN; ++qq) {
            float    v  = kb[base + qq];
            int      ii = (int)ib[base + qq];
            bool ins = (v < fv[KNN - 1]) || (v == fv[KNN - 1] && ii < fi[KNN - 1]);
            if (ins) {
                fv[KNN - 1] = v; fi[KNN - 1] = ii;
                #pragma unroll
                for (int p = KNN - 1; p > 0; --p) {
                    float va = fv[p - 1], vb = fv[p];
                    int   ia = fi[p - 1], ic = fi[p];
                    bool sw = (vb < va) || (vb == va && ic < ia);
                    fv[p - 1] = sw ? vb : va; fv[p] = sw ? va : vb;
                    fi[p - 1] = sw ? ic : ia; fi[p] = sw ? ia : ic;
                }
            }
        }
        int* op = idxout + ((size_t)(b * N_PTS + row0 + tid)) * KNN;
        #pragma unroll
        for (int p = 0; p < KNN; ++p) op[p] = fi[p];
    }
}

// ---------------------------------------------------------------------------
// MFMA feature GEMM: out[m,c] = sum_k A[m,k]*W[c,k], bf16 hi/lo 3-pass.
__launch_bounds__(256)
__global__ void fgemm(const unsigned short* __restrict__ Ah, const unsigned short* __restrict__ Al,
                      int strideA, int K,
                      const unsigned short* __restrict__ Wh, const unsigned short* __restrict__ Wl,
                      int C, float* __restrict__ out, int fuse_bn,
                      const float* __restrict__ g, const float* __restrict__ beta) {
    __shared__ unsigned short AhS[128 * 40];
    __shared__ unsigned short AlS[128 * 40];
    __shared__ unsigned short BhS[128 * 40];
    __shared__ unsigned short BlS[128 * 40];

    const int c0 = blockIdx.x * 128;
    const int m0 = blockIdx.y * 128;
    const int tid = threadIdx.x;
    const int w = tid >> 6, lane = tid & 63;
    const int n = lane & 15, q = lane >> 4;

    float4v acc[2][8];
    #pragma unroll
    for (int rt = 0; rt < 2; ++rt)
        #pragma unroll
        for (int ct = 0; ct < 8; ++ct) acc[rt][ct] = (float4v){0.f, 0.f, 0.f, 0.f};

    for (int kk = 0; kk < K; kk += 32) {
        __syncthreads();
        for (int tt = tid; tt < 512; tt += 256) {
            int rr = tt >> 2, c8 = tt & 3;
            size_t oa = (size_t)(m0 + rr) * strideA + kk + c8 * 8;
            *(short8*)&AhS[rr * 40 + c8 * 8] = *(const short8*)(Ah + oa);
            *(short8*)&AlS[rr * 40 + c8 * 8] = *(const short8*)(Al + oa);
            size_t ob = (size_t)(c0 + rr) * K + kk + c8 * 8;
            *(short8*)&BhS[rr * 40 + c8 * 8] = *(const short8*)(Wh + ob);
            *(short8*)&BlS[rr * 40 + c8 * 8] = *(const short8*)(Wl + ob);
        }
        __syncthreads();

        short8 af[2][2];
        #pragma unroll
        for (int rt = 0; rt < 2; ++rt) {
            af[rt][0] = *(const short8*)&AhS[(w * 32 + rt * 16 + n) * 40 + q * 8];
            af[rt][1] = *(const short8*)&AlS[(w * 32 + rt * 16 + n) * 40 + q * 8];
        }
        #pragma unroll
        for (int ct = 0; ct < 8; ++ct) {
            short8 bh = *(const short8*)&BhS[(ct * 16 + n) * 40 + q * 8];
            short8 bl = *(const short8*)&BlS[(ct * 16 + n) * 40 + q * 8];
            #pragma unroll
            for (int rt = 0; rt < 2; ++rt) {
                acc[rt][ct] = __builtin_amdgcn_mfma_f32_16x16x32_bf16(af[rt][0], bh, acc[rt][ct], 0, 0, 0);
                acc[rt][ct] = __builtin_amdgcn_mfma_f32_16x16x32_bf16(af[rt][1], bh, acc[rt][ct], 0, 0, 0);
                acc[rt][ct] = __builtin_amdgcn_mfma_f32_16x16x32_bf16(af[rt][0], bl, acc[rt][ct], 0, 0, 0);
            }
        }
    }

    #pragma unroll
    for (int rt = 0; rt < 2; ++rt)
        #pragma unroll
        for (int ct = 0; ct < 8; ++ct) {
            int c = c0 + ct * 16 + n;
            float sc = 1.f, bt = 0.f;
            if (fuse_bn) { sc = g[c] / sqrtf(1.f + EPS_BN); bt = beta[c]; }
            #pragma unroll
            for (int e = 0; e < 4; ++e) {
                int m = m0 + w * 32 + rt * 16 + q * 4 + e;
                float v = acc[rt][ct][e];
                if (fuse_bn) { v = v * sc + bt; v = (v >= 0.f) ? v : SLOPE * v; }
                out[(size_t)m * C + c] = v;
            }
        }
}

// ---------------------------------------------------------------------------
// EdgeConv max-pool epilogue -> bf16 hi/lo feature rows
__global__ void pool_kernel(const float* __restrict__ zc2, int Co,
                            const int* __restrict__ idx,
                            const float* __restrict__ g, const float* __restrict__ beta,
                            unsigned short* __restrict__ hh, unsigned short* __restrict__ hl,
                            int hoff) {
    int n = blockIdx.x, b = blockIdx.y;
    int o = threadIdx.x;
    size_t bn = (size_t)b * N_PTS + n;
    const int* ip = idx + bn * KNN;
    float zn   = zc2[bn * (size_t)(2 * Co) + o];
    float base = zc2[bn * (size_t)(2 * Co) + Co + o] - zn;
    float m = -INFINITY;
    #pragma unroll
    for (int j = 0; j < KNN; ++j) {
        size_t rr = (size_t)b * N_PTS + ip[j];
        m = fmaxf(m, zc2[rr * (size_t)(2 * Co) + o]);
    }
    float y = m + base;
    float sc = g[o] / sqrtf(1.f + EPS_BN);
    y = y * sc + beta[o];
    y = (y >= 0.f) ? y : SLOPE * y;
    unsigned short h = f2bf(y);
    hh[bn * 512 + hoff + o] = h;
    hl[bn * 512 + hoff + o] = f2bf(y - bf2f(h));
}

// ---------------------------------------------------------------------------
// final global max/mean over N: two-stage (32 chunks of 128 rows)
__global__ void reduce_partial(const float* __restrict__ y5,
                               float* __restrict__ pmax, float* __restrict__ psum) {
    int chunk = blockIdx.x, b = blockIdx.y, c = threadIdx.x;
    float mx = -INFINITY, sm = 0.f;
    for (int qq = 0; qq < 128; ++qq) {
        int n = chunk * 128 + qq;
        float v = y5[((size_t)b * N_PTS + n) * 512 + c];
        mx = fmaxf(mx, v);
        sm += v;
    }
    pmax[((size_t)b * 32 + chunk) * 512 + c] = mx;
    psum[((size_t)b * 32 + chunk) * 512 + c] = sm;
}

__global__ void reduce_final(const float* __restrict__ pmax,
                             const float* __restrict__ psum,
                             float* __restrict__ out) {
    int i = blockIdx.x * blockDim.x + threadIdx.x;
    if (i >= BATCH * 512) return;
    int b = i / 512, c = i % 512;
    float mx = -INFINITY, sm = 0.f;
    for (int qq = 0; qq < 32; ++qq) {
        mx = fmaxf(mx, pmax[((size_t)b * 32 + qq) * 512 + c]);
        sm += psum[((size_t)b * 32 + qq) * 512 + c];
    }
    out[(size_t)b * 1024 + c] = mx;
    out[(size_t)b * 1024 + 512 + c] = sm * (1.f / 4096.f);
}

// ---------------------------------------------------------------------------
extern "C" void kernel_launch(void* const* d_in, const int* in_sizes, int n_in,
                              void* d_out, int out_size, void* d_ws, size_t ws_size,
                              hipStream_t stream) {
    const float* x = (const float*)d_in[0];
    const float* W[5], *gg[5], *bb[5];
    for (int i = 0; i < 5; ++i) {
        W[i]  = (const float*)d_in[2 + 3 * i];
        gg[i] = (const float*)d_in[3 + 3 * i];
        bb[i] = (const float*)d_in[4 + 3 * i];
    }
    float* outp = (float*)d_out;

    char* wsb = (char*)d_ws;
    size_t off = 0;
    unsigned short* x1h = (unsigned short*)(wsb + off); off += (size_t)M_ROWS * 32 * 2;
    unsigned short* x1l = (unsigned short*)(wsb + off); off += (size_t)M_ROWS * 32 * 2;
    float* sq = (float*)(wsb + off); off += (size_t)M_ROWS * 4;
    int*   idx = (int*)(wsb + off); off += (size_t)M_ROWS * KNN * 4;
    unsigned short* Wh = (unsigned short*)(wsb + off); off += (size_t)512 * 512 * 2;
    unsigned short* Wl = (unsigned short*)(wsb + off); off += (size_t)512 * 512 * 2;
    unsigned short* hh = (unsigned short*)(wsb + off); off += (size_t)M_ROWS * 512 * 2;
    unsigned short* hl = (unsigned short*)(wsb + off); off += (size_t)M_ROWS * 512 * 2;
    float* zc2 = (float*)(wsb + off); off += (size_t)M_ROWS * 512 * 4;
    float* pmx = (float*)(wsb + off); off += (size_t)BATCH * 32 * 512 * 4;
    float* psm = (float*)(wsb + off); off += (size_t)BATCH * 32 * 512 * 4;
    (void)ws_size; (void)in_sizes; (void)n_in; (void)out_size;

    convert_x1<<<(M_ROWS + 255) / 256, 256, 0, stream>>>(x, x1h, x1l, sq);

    struct L { int D, Co, KP, hoff; };
    const L layers[4] = { {3, 64, 32, 0}, {64, 64, 64, 64}, {64, 128, 64, 128}, {128, 256, 128, 256} };

    for (int li = 0; li < 4; ++li) {
        const L& ly = layers[li];
        const unsigned short* Ahp;
        const unsigned short* Alp;
        int strideA;
        if (li == 0) { Ahp = x1h; Alp = x1l; strideA = 32; }
        else {
            int po = layers[li - 1].hoff;
            Ahp = hh + po; Alp = hl + po; strideA = 512;
            sqnorm_hl<<<M_ROWS / 4, 256, 0, stream>>>(Ahp, Alp, ly.D, sq);
        }

        if (li == 0)
            knn_mfma<32><<<dim3(N_PTS / 64, BATCH), 256, 0, stream>>>(Ahp, Alp, strideA, sq, idx);
        else if (ly.D == 64)
            knn_mfma<64><<<dim3(N_PTS / 64, BATCH), 256, 0, stream>>>(Ahp, Alp, strideA, sq, idx);
        else
            knn_mfma<128><<<dim3(N_PTS / 64, BATCH), 256, 0, stream>>>(Ahp, Alp, strideA, sq, idx);

        repack_edge_split<<<(2 * ly.Co * ly.KP + 255) / 256, 256, 0, stream>>>(
            W[li], ly.Co, ly.D, ly.KP, Wh, Wl);
        fgemm<<<dim3((2 * ly.Co) / 128, M_ROWS / 128), 256, 0, stream>>>(
            Ahp, Alp, strideA, ly.KP, Wh, Wl, 2 * ly.Co, zc2, 0, nullptr, nullptr);
        pool_kernel<<<dim3(N_PTS, BATCH), ly.Co, 0, stream>>>(
            zc2, ly.Co, idx, gg[li], bb[li], hh, hl, ly.hoff);
    }

    // layer 5
    repack_w5_split<<<(512 * 512 + 255) / 256, 256, 0, stream>>>(W[4], Wh, Wl);
    fgemm<<<dim3(4, M_ROWS / 128), 256, 0, stream>>>(
        hh, hl, 512, 512, Wh, Wl, 512, zc2, 1, gg[4], bb[4]);

    reduce_partial<<<dim3(32, BATCH), 512, 0, stream>>>(zc2, pmx, psm);
    reduce_final<<<(BATCH * 512 + 255) / 256, 256, 0, stream>>>(pmx, psm, outp);
}